// Round 1
// baseline (277.631 us; speedup 1.0000x reference)
//
#include <hip/hip_runtime.h>
#include <stdint.h>

// ---------------------------------------------------------------------------
// HandcraftedKeyModel: clamped-decay scan (12 keys) + per-step [12]@[12,84].
//
// Exact parallel scan: h -> min(d*h + b, 5) closes under composition as the
// triple (A,B,C) meaning h -> min(A*h+B, C).  A per chunk is d^L (constant).
// Output is computed incrementally: out_j(t) = d*out_j(t-1) + coef(t)*W[k(t)][j],
// coef(t) = 1 + (clamped - linear) for the single hit key (only key that can
// clamp, since h<=5 always => d*h < 5 for non-hit keys).
// ---------------------------------------------------------------------------

#define NKEY 12
#define NOUT 84           // 7 modes * 12 scales
#define LC   64           // compose-chunk length (K1/K2/K3 granularity)
#define LR   128          // replay-chunk length (K4 granularity)
#define GROUPS 64         // K2 groups

constexpr float DECAYF = 0.99950012497916927f;   // exp(-0.0005)
constexpr float BIGC   = 1e30f;                  // "no clamp yet"

constexpr float cpowf(float a, int n) {
    float r = 1.0f;
    for (int i = 0; i < n; ++i) r *= a;
    return r;
}
constexpr float A64F   = cpowf(DECAYF, LC);      // d^64
constexpr float AG128F = cpowf(A64F, 128);       // d^(64*128), for nc/GROUPS==128

// --------------------------- K1: per-chunk compose -------------------------
// One thread per LC-chunk: compose 64 step-maps into (B[12], C[12]).
__global__ __launch_bounds__(128) void k_compose(const int* __restrict__ seq,
                                                 float* __restrict__ Bc,
                                                 float* __restrict__ Cc,
                                                 int nc) {
    int c = blockIdx.x * blockDim.x + threadIdx.x;
    if (c >= nc) return;
    const float D = DECAYF;
    float B[NKEY], C[NKEY];
#pragma unroll
    for (int k = 0; k < NKEY; ++k) { B[k] = 0.0f; C[k] = BIGC; }

    const int4* s4 = reinterpret_cast<const int4*>(seq) + c * (LC / 4);
    for (int q = 0; q < LC / 4; ++q) {
        int4 v4 = s4[q];
        int vv[4] = {v4.x, v4.y, v4.z, v4.w};
#pragma unroll
        for (int u = 0; u < 4; ++u) {
            int note = vv[u];
            bool valid = note > -10000;
            int m = note % NKEY; if (m < 0) m += NKEY;
#pragma unroll
            for (int k = 0; k < NKEY; ++k) {
                float b = (valid && (m == k)) ? 1.0f : 0.0f;
                B[k] = fmaf(B[k], D, b);
                C[k] = fminf(fmaf(C[k], D, b), 5.0f);
            }
        }
    }
#pragma unroll
    for (int k = 0; k < NKEY; ++k) {
        Bc[c * NKEY + k] = B[k];
        Cc[c * NKEY + k] = C[k];
    }
}

// --------------------------- K2: scan over chunks --------------------------
// Single block, 768 threads = (g in 0..63) x (k in 0..11).
// Emits hstart[c][k] = h at the START of chunk c (applied to h0 = 0).
__global__ __launch_bounds__(GROUPS * NKEY) void k_scan(const float* __restrict__ Bc,
                                                        const float* __restrict__ Cc,
                                                        float* __restrict__ hstart,
                                                        int nc) {
    __shared__ float BG[GROUPS][NKEY], CG[GROUPS][NKEY];
    __shared__ float BP[GROUPS][NKEY], CP[GROUPS][NKEY];
    const int tid = threadIdx.x;
    const int g = tid / NKEY, k = tid % NKEY;
    const float A = A64F;
    const int per = nc / GROUPS;
    const float Ag = (per == 128) ? AG128F : __powf(A64F, (float)per);

    // Phase A: each thread composes its group's chunks.
    {
        float B = 0.0f, C = BIGC;
        int c0 = g * per;
        for (int i = 0; i < per; ++i) {
            float B1 = Bc[(c0 + i) * NKEY + k];
            float C1 = Cc[(c0 + i) * NKEY + k];
            B = fmaf(A, B, B1);
            C = fminf(fmaf(A, C, B1), C1);
        }
        BG[g][k] = B; CG[g][k] = C;
    }
    __syncthreads();

    // Phase B: 12 threads scan the 64 group-totals -> exclusive group prefixes.
    if (tid < NKEY) {
        float B = 0.0f, C = BIGC;
        for (int g2 = 0; g2 < GROUPS; ++g2) {
            BP[g2][tid] = B; CP[g2][tid] = C;
            float B1 = BG[g2][tid], C1 = CG[g2][tid];
            B = fmaf(Ag, B, B1);
            C = fminf(fmaf(Ag, C, B1), C1);
        }
    }
    __syncthreads();

    // Phase C: re-walk, emitting h at each chunk start.
    {
        float B = BP[g][k], C = CP[g][k];
        int c0 = g * per;
        for (int i = 0; i < per; ++i) {
            hstart[(c0 + i) * NKEY + k] = fminf(B, C);
            float B1 = Bc[(c0 + i) * NKEY + k];
            float C1 = Cc[(c0 + i) * NKEY + k];
            B = fmaf(A, B, B1);
            C = fminf(fmaf(A, C, B1), C1);
        }
    }
}

// --------------------------- K3: per-step (k, coef) ------------------------
// One block (1 wave) per LC-chunk; lanes 0..11 own one key each and replay
// the chunk exactly, recording coef = 1 + (clamped - linear) for the hit key.
__global__ __launch_bounds__(64) void k_coef(const int* __restrict__ seq,
                                             const float* __restrict__ hstart,
                                             uint2* __restrict__ sinfo) {
    int c = blockIdx.x;
    int lane = threadIdx.x;
    if (lane >= NKEY) return;
    const float D = DECAYF;
    float h = hstart[c * NKEY + lane];
    int base = c * LC;
    for (int i = 0; i < LC; ++i) {
        int note = seq[base + i];
        bool valid = note > -10000;
        int m = note % NKEY; if (m < 0) m += NKEY;
        float b = (valid && (m == lane)) ? 1.0f : 0.0f;
        float hlin = fmaf(h, D, b);
        h = fminf(hlin, 5.0f);
        if (valid) {
            if (m == lane) {
                float coef = 1.0f + (h - hlin);   // 1 if no clamp, else <=1
                sinfo[base + i] = make_uint2((unsigned)(m * NOUT),
                                             __float_as_uint(coef));
            }
        } else if (lane == 0) {
            sinfo[base + i] = make_uint2(0u, 0u); // coef = 0.0f
        }
    }
}

// --------------------------- K4: stream the output -------------------------
// One block per LR-chunk; thread j owns output column j (j < 84).
// out_j(t) = d*out_j(t-1) + coef(t)*W[k(t)][j], seeded by a 12-FMA dot with
// hstart at the chunk boundary.
__global__ __launch_bounds__(128) void k_out(const float* __restrict__ W,
                                             const float* __restrict__ hstart,
                                             const uint2* __restrict__ sinfo,
                                             float* __restrict__ out) {
    __shared__ float WL[NKEY * NOUT];
    const int c = blockIdx.x;
    const int j = threadIdx.x;
    for (int i = j; i < NKEY * NOUT; i += 128) WL[i] = W[i];
    __syncthreads();
    if (j >= NOUT) return;

    const float D = DECAYF;
    const int t0 = c * LR;
    float o = 0.0f;
#pragma unroll
    for (int k = 0; k < NKEY; ++k)
        o = fmaf(hstart[(t0 / LC) * NKEY + k], WL[k * NOUT + j], o);

    float* op = out + (size_t)t0 * NOUT + j;
#pragma unroll 4
    for (int i = 0; i < LR; ++i) {
        uint2 info = sinfo[t0 + i];
        float coef = __uint_as_float(info.y);
        o = fmaf(o, D, coef * WL[info.x + j]);
        *op = o;
        op += NOUT;
    }
}

// ---------------------------------------------------------------------------
extern "C" void kernel_launch(void* const* d_in, const int* in_sizes, int n_in,
                              void* d_out, int out_size, void* d_ws, size_t ws_size,
                              hipStream_t stream) {
    const int*   seq = (const int*)d_in[0];
    const float* W   = (const float*)d_in[1];
    float*       out = (float*)d_out;

    const int T  = in_sizes[0];     // 524288
    const int nc = T / LC;          // 8192 compose chunks
    const int nr = T / LR;          // 4096 replay chunks

    float* Bc = (float*)d_ws;                  // nc*12 floats
    float* Cc = Bc + (size_t)nc * NKEY;        // nc*12 floats
    float* hs = Cc + (size_t)nc * NKEY;        // nc*12 floats
    uint2* si = (uint2*)(hs + (size_t)nc * NKEY);  // T uint2 (8B each)

    hipLaunchKernelGGL(k_compose, dim3((nc + 127) / 128), dim3(128), 0, stream,
                       seq, Bc, Cc, nc);
    hipLaunchKernelGGL(k_scan, dim3(1), dim3(GROUPS * NKEY), 0, stream,
                       Bc, Cc, hs, nc);
    hipLaunchKernelGGL(k_coef, dim3(nc), dim3(64), 0, stream, seq, hs, si);
    hipLaunchKernelGGL(k_out, dim3(nr), dim3(128), 0, stream, W, hs, si, out);
}

// Round 2
// 248.639 us; speedup vs baseline: 1.1166x; 1.1166x over previous
//
#include <hip/hip_runtime.h>
#include <stdint.h>

// ---------------------------------------------------------------------------
// HandcraftedKeyModel: clamped-decay scan (12 keys) + per-step [12]@[12,84].
//
// Exact parallel scan: h -> min(d*h + b, 5) closes under composition as the
// triple (A,B,C) meaning h -> min(A*h+B, C); A per chunk is d^L (constant).
//   K1: per-64-chunk compose -> (B[12], C[12])            [8192 chunks]
//   K2: scan over chunks -> h at every chunk start        [1 block]
//   K34 (fused): per chunk, 12 lanes replay 64 steps into LDS heats[64][12],
//        then 252 threads compute out[64][84] = heats @ W with W quads in
//        registers and fully-contiguous float4 stores (1 KiB per wave-store).
//        No serial-in-t output recurrence, no sinfo round-trip.
// ---------------------------------------------------------------------------

#define NKEY 12
#define NOUT 84           // 7 modes * 12 scales
#define LC   64           // chunk length
#define GROUPS 64         // K2 groups

constexpr float DECAYF = 0.99950012497916927f;   // exp(-0.0005)
constexpr float BIGC   = 1e30f;                  // "no clamp yet"

constexpr float cpowf(float a, int n) {
    float r = 1.0f;
    for (int i = 0; i < n; ++i) r *= a;
    return r;
}
constexpr float A64F   = cpowf(DECAYF, LC);      // d^64
constexpr float AG128F = cpowf(A64F, 128);       // d^(64*128) for nc/GROUPS==128

// --------------------------- K1: per-chunk compose -------------------------
__global__ __launch_bounds__(128) void k_compose(const int* __restrict__ seq,
                                                 float* __restrict__ Bc,
                                                 float* __restrict__ Cc,
                                                 int nc) {
    int c = blockIdx.x * blockDim.x + threadIdx.x;
    if (c >= nc) return;
    const float D = DECAYF;
    float B[NKEY], C[NKEY];
#pragma unroll
    for (int k = 0; k < NKEY; ++k) { B[k] = 0.0f; C[k] = BIGC; }

    const int4* s4 = reinterpret_cast<const int4*>(seq) + c * (LC / 4);
    for (int q = 0; q < LC / 4; ++q) {
        int4 v4 = s4[q];
        int vv[4] = {v4.x, v4.y, v4.z, v4.w};
#pragma unroll
        for (int u = 0; u < 4; ++u) {
            int note = vv[u];
            bool valid = note > -10000;
            int m = note % NKEY; if (m < 0) m += NKEY;
#pragma unroll
            for (int k = 0; k < NKEY; ++k) {
                float b = (valid && (m == k)) ? 1.0f : 0.0f;
                B[k] = fmaf(B[k], D, b);
                C[k] = fminf(fmaf(C[k], D, b), 5.0f);
            }
        }
    }
#pragma unroll
    for (int k = 0; k < NKEY; ++k) {
        Bc[c * NKEY + k] = B[k];
        Cc[c * NKEY + k] = C[k];
    }
}

// --------------------------- K2: scan over chunks --------------------------
// Single block, 768 threads = (g in 0..63) x (k in 0..11).
// Emits hstart[c][k] = h at the START of chunk c (applied to h0 = 0).
__global__ __launch_bounds__(GROUPS * NKEY) void k_scan(const float* __restrict__ Bc,
                                                        const float* __restrict__ Cc,
                                                        float* __restrict__ hstart,
                                                        int nc) {
    __shared__ float BG[GROUPS][NKEY], CG[GROUPS][NKEY];
    __shared__ float BP[GROUPS][NKEY], CP[GROUPS][NKEY];
    const int tid = threadIdx.x;
    const int g = tid / NKEY, k = tid % NKEY;
    const float A = A64F;
    const int per = nc / GROUPS;
    const float Ag = (per == 128) ? AG128F : __powf(A64F, (float)per);

    {   // Phase A: each thread composes its group's chunks.
        float B = 0.0f, C = BIGC;
        int c0 = g * per;
        for (int i = 0; i < per; ++i) {
            float B1 = Bc[(c0 + i) * NKEY + k];
            float C1 = Cc[(c0 + i) * NKEY + k];
            B = fmaf(A, B, B1);
            C = fminf(fmaf(A, C, B1), C1);
        }
        BG[g][k] = B; CG[g][k] = C;
    }
    __syncthreads();

    // Phase B: 12 threads scan the 64 group-totals -> exclusive group prefixes.
    if (tid < NKEY) {
        float B = 0.0f, C = BIGC;
        for (int g2 = 0; g2 < GROUPS; ++g2) {
            BP[g2][tid] = B; CP[g2][tid] = C;
            float B1 = BG[g2][tid], C1 = CG[g2][tid];
            B = fmaf(Ag, B, B1);
            C = fminf(fmaf(Ag, C, B1), C1);
        }
    }
    __syncthreads();

    {   // Phase C: re-walk, emitting h at each chunk start.
        float B = BP[g][k], C = CP[g][k];
        int c0 = g * per;
        for (int i = 0; i < per; ++i) {
            hstart[(c0 + i) * NKEY + k] = fminf(B, C);
            float B1 = Bc[(c0 + i) * NKEY + k];
            float C1 = Cc[(c0 + i) * NKEY + k];
            B = fmaf(A, B, B1);
            C = fminf(fmaf(A, C, B1), C1);
        }
    }
}

// --------------------- K34: fused replay + [12]@[12,84] --------------------
// One block per 64-chunk. Wave 0: stage seq->LDS, 12 lanes replay exactly,
// writing heats[64][12] to LDS. Then 252 threads (r=row-class 0..11,
// q=col-quad 0..20) compute float4 outputs; W quads live in 48 VGPRs.
// Wave-store pattern: rows r,r+1,r+2 per wave -> 1024 contiguous bytes.
__global__ __launch_bounds__(256) void k_out_fused(const int* __restrict__ seq,
                                                   const float* __restrict__ W,
                                                   const float* __restrict__ hstart,
                                                   float* __restrict__ out) {
    __shared__ float heats[LC][NKEY];   // 3 KiB, row stride 48 B (16B-aligned)
    __shared__ int   notes[LC];
    const int c   = blockIdx.x;
    const int tid = threadIdx.x;
    const int q = tid % 21;             // column quad 0..20
    const int r = tid / 21;             // row class 0..12 (12 => idle)

    // All threads: pull their W column-quads into registers (4 KiB, L1/L2 hot).
    float4 w4[NKEY];
#pragma unroll
    for (int k = 0; k < NKEY; ++k)
        w4[k] = reinterpret_cast<const float4*>(W + k * NOUT)[q];

    // Wave 0: stage the chunk's notes, then exact 64-step replay (lanes 0..11).
    if (tid < LC / 4) {
        int4 v = reinterpret_cast<const int4*>(seq + (size_t)c * LC)[tid];
        reinterpret_cast<int4*>(notes)[tid] = v;
    }
    if (tid < NKEY) {
        float h = hstart[c * NKEY + tid];
        const float D = DECAYF;
        for (int i = 0; i < LC; ++i) {
            int note = notes[i];                   // same-wave LDS, ordered
            bool valid = note > -10000;
            int m = note % NKEY; if (m < 0) m += NKEY;
            float b = (valid && (m == tid)) ? 1.0f : 0.0f;
            h = fminf(fmaf(h, D, b), 5.0f);
            heats[i][tid] = h;
        }
    }
    __syncthreads();
    if (tid >= 252) return;

    float* const op = out + (size_t)c * (LC * NOUT) + q * 4;

    auto emit_row = [&](int row) {
        const float4* hv = reinterpret_cast<const float4*>(&heats[row][0]);
        float4 h0 = hv[0], h1 = hv[1], h2 = hv[2];
        const float hk[NKEY] = {h0.x, h0.y, h0.z, h0.w,
                                h1.x, h1.y, h1.z, h1.w,
                                h2.x, h2.y, h2.z, h2.w};
        float4 o; o.x = o.y = o.z = o.w = 0.0f;
#pragma unroll
        for (int k = 0; k < NKEY; ++k) {
            o.x = fmaf(hk[k], w4[k].x, o.x);
            o.y = fmaf(hk[k], w4[k].y, o.y);
            o.z = fmaf(hk[k], w4[k].z, o.z);
            o.w = fmaf(hk[k], w4[k].w, o.w);
        }
        *reinterpret_cast<float4*>(op + row * NOUT) = o;
    };

#pragma unroll
    for (int s = 0; s < 5; ++s) emit_row(r + 12 * s);  // rows 0..59
    if (r < 4) emit_row(60 + r);                       // rows 60..63
}

// ---------------------------------------------------------------------------
extern "C" void kernel_launch(void* const* d_in, const int* in_sizes, int n_in,
                              void* d_out, int out_size, void* d_ws, size_t ws_size,
                              hipStream_t stream) {
    const int*   seq = (const int*)d_in[0];
    const float* W   = (const float*)d_in[1];
    float*       out = (float*)d_out;

    const int T  = in_sizes[0];     // 524288
    const int nc = T / LC;          // 8192 chunks

    float* Bc = (float*)d_ws;                  // nc*12 floats
    float* Cc = Bc + (size_t)nc * NKEY;        // nc*12 floats
    float* hs = Cc + (size_t)nc * NKEY;        // nc*12 floats

    hipLaunchKernelGGL(k_compose, dim3((nc + 127) / 128), dim3(128), 0, stream,
                       seq, Bc, Cc, nc);
    hipLaunchKernelGGL(k_scan, dim3(1), dim3(GROUPS * NKEY), 0, stream,
                       Bc, Cc, hs, nc);
    hipLaunchKernelGGL(k_out_fused, dim3(nc), dim3(256), 0, stream,
                       seq, W, hs, out);
}

// Round 6
// 206.988 us; speedup vs baseline: 1.3413x; 1.2012x over previous
//
#include <hip/hip_runtime.h>
#include <stdint.h>

// ---------------------------------------------------------------------------
// HandcraftedKeyModel: clamped-decay scan (12 keys) + per-step [12]@[12,84].
//
// h -> min(d*h + b, 5) closes under composition as (A,B,C): h -> min(A*h+B,C).
// All elements at a given level share the same A (d^L), so a triple is (B,C).
// 3-level exact scan, fully distributed (no single-CU 768 KB gather):
//   KA : per-64-step chunk compose -> Bc/Cc (k-major) + per-32-chunk group
//        totals via LDS -> BG/CG [12][256].
//   KB : one block PER KEY (12 blocks): super-compose(16x16) -> scan 16 ->
//        rewalk -> vstart[256] in LDS -> 256 threads walk 32 chunks each,
//        emitting hs[c][12] (value at every chunk start).
//   KC : per chunk: 12 lanes replay 64 steps exactly into LDS heats[64][12],
//        then 252 threads compute out = heats @ W (W quads in 48 VGPRs),
//        1 KiB contiguous float4 stores per wave.
// ---------------------------------------------------------------------------

#define NKEY 12
#define NOUT 84           // 7 modes * 12 scales
#define LC   64           // steps per chunk
#define GSZ  32           // chunks per group
#define NGRP 256          // groups (8192/32)
#define NSUP 16           // supers (256/16)

constexpr double DECAYD = 0.9995001249791693;    // exp(-0.0005)
constexpr float  DECAYF = (float)DECAYD;
constexpr float  BIGC   = 1e30f;

constexpr float cpowf(int n) {        // d^n via double chain -> float
    double r = 1.0;
    for (int i = 0; i < n; ++i) r *= DECAYD;
    return (float)r;
}
constexpr float A64 = cpowf(LC);              // d^64     (chunk A)
constexpr float AG  = cpowf(LC * GSZ);        // d^2048   (group A)
constexpr float AS  = cpowf(LC * GSZ * NSUP); // d^32768  (super A)

// ------------------- KA: chunk compose + group totals ----------------------
__global__ __launch_bounds__(128) void kA(const int* __restrict__ seq,
                                          float* __restrict__ Bc,
                                          float* __restrict__ Cc,
                                          float* __restrict__ BG,
                                          float* __restrict__ CG,
                                          int nc) {
    const int tid = threadIdx.x;
    const int c   = blockIdx.x * 128 + tid;      // chunk id
    const float D = DECAYF;
    float B[NKEY], C[NKEY];
#pragma unroll
    for (int k = 0; k < NKEY; ++k) { B[k] = 0.0f; C[k] = BIGC; }

    const int4* s4 = reinterpret_cast<const int4*>(seq) + c * (LC / 4);
    for (int q = 0; q < LC / 4; ++q) {
        int4 v4 = s4[q];
        int vv[4] = {v4.x, v4.y, v4.z, v4.w};
#pragma unroll
        for (int u = 0; u < 4; ++u) {
            int note = vv[u];
            bool valid = note > -10000;
            int m = note % NKEY; if (m < 0) m += NKEY;
#pragma unroll
            for (int k = 0; k < NKEY; ++k) {
                float b = (valid && (m == k)) ? 1.0f : 0.0f;
                B[k] = fmaf(B[k], D, b);
                C[k] = fminf(fmaf(C[k], D, b), 5.0f);
            }
        }
    }
    // coalesced k-major stores
#pragma unroll
    for (int k = 0; k < NKEY; ++k) {
        Bc[k * nc + c] = B[k];
        Cc[k * nc + c] = C[k];
    }

    // in-block group totals (128 chunks = 4 groups of 32)
    __shared__ float LB[128][NKEY], LX[128][NKEY];   // 12 KiB
#pragma unroll
    for (int k = 0; k < NKEY; ++k) { LB[tid][k] = B[k]; LX[tid][k] = C[k]; }
    __syncthreads();
    if (tid < 4 * NKEY) {
        const int Gl = tid / NKEY, k = tid % NKEY;
        float b = 0.0f, cc = BIGC;
        const int base = Gl * GSZ;
        for (int i = 0; i < GSZ; ++i) {
            float b1 = LB[base + i][k], c1 = LX[base + i][k];
            b  = fmaf(A64, b, b1);
            cc = fminf(fmaf(A64, cc, b1), c1);
        }
        const int G = blockIdx.x * 4 + Gl;
        BG[k * NGRP + G] = b;
        CG[k * NGRP + G] = cc;
    }
}

// ---------------- KB: per-key scan -> per-chunk start values ---------------
__global__ __launch_bounds__(256) void kB(const float* __restrict__ Bc,
                                          const float* __restrict__ Cc,
                                          const float* __restrict__ BG,
                                          const float* __restrict__ CG,
                                          float* __restrict__ hs,
                                          int nc) {
    const int k   = blockIdx.x;          // 0..11
    const int tid = threadIdx.x;
    __shared__ float SB[NSUP], SC[NSUP], PB[NSUP], PC[NSUP], VST[NGRP];

    if (tid < NSUP) {                    // super-compose (16 groups each)
        float b = 0.0f, c = BIGC;
        for (int i = 0; i < NGRP / NSUP; ++i) {
            const int G = tid * (NGRP / NSUP) + i;
            float b1 = BG[k * NGRP + G], c1 = CG[k * NGRP + G];
            b = fmaf(AG, b, b1);
            c = fminf(fmaf(AG, c, b1), c1);
        }
        SB[tid] = b; SC[tid] = c;
    }
    __syncthreads();
    if (tid == 0) {                      // scan 16 supers (exclusive)
        float b = 0.0f, c = BIGC;
        for (int s = 0; s < NSUP; ++s) {
            PB[s] = b; PC[s] = c;
            float b1 = SB[s], c1 = SC[s];
            b = fmaf(AS, b, b1);
            c = fminf(fmaf(AS, c, b1), c1);
        }
    }
    __syncthreads();
    if (tid < NSUP) {                    // rewalk supers -> group-start values
        float b = PB[tid], c = PC[tid];
        for (int i = 0; i < NGRP / NSUP; ++i) {
            const int G = tid * (NGRP / NSUP) + i;
            VST[G] = fminf(b, c);
            float b1 = BG[k * NGRP + G], c1 = CG[k * NGRP + G];
            b = fmaf(AG, b, b1);
            c = fminf(fmaf(AG, c, b1), c1);
        }
    }
    __syncthreads();
    {                                    // thread g walks group g's 32 chunks
        const int g = tid;
        float v = VST[g];
        const int c0 = g * GSZ;
        for (int i = 0; i < GSZ; ++i) {
            hs[(size_t)(c0 + i) * NKEY + k] = v;
            float b1 = Bc[k * nc + c0 + i], c1 = Cc[k * nc + c0 + i];
            v = fminf(fmaf(A64, v, b1), c1);
        }
    }
}

// ------------------- KC: fused replay + [12]@[12,84] -----------------------
__global__ __launch_bounds__(256) void kC(const int* __restrict__ seq,
                                          const float* __restrict__ W,
                                          const float* __restrict__ hs,
                                          float* __restrict__ out) {
    __shared__ float heats[LC][NKEY];   // 3 KiB, row stride 48 B
    __shared__ int   notes[LC];
    const int c   = blockIdx.x;
    const int tid = threadIdx.x;
    const int q = tid % 21;             // column quad 0..20
    const int r = tid / 21;             // row class 0..12 (12 => idle tail)

    float4 w4[NKEY];                    // 48 VGPRs of W quads
#pragma unroll
    for (int k = 0; k < NKEY; ++k)
        w4[k] = reinterpret_cast<const float4*>(W + k * NOUT)[q];

    if (tid < LC / 4) {
        int4 v = reinterpret_cast<const int4*>(seq + (size_t)c * LC)[tid];
        reinterpret_cast<int4*>(notes)[tid] = v;
    }
    if (tid < NKEY) {                   // exact 64-step replay, lanes 0..11
        float h = hs[(size_t)c * NKEY + tid];
        const float D = DECAYF;
        for (int i = 0; i < LC; ++i) {
            int note = notes[i];        // same-wave LDS, ordered
            bool valid = note > -10000;
            int m = note % NKEY; if (m < 0) m += NKEY;
            float b = (valid && (m == tid)) ? 1.0f : 0.0f;
            h = fminf(fmaf(h, D, b), 5.0f);
            heats[i][tid] = h;
        }
    }
    __syncthreads();
    if (tid >= 252) return;

    float* const op = out + (size_t)c * (LC * NOUT) + q * 4;

    auto emit_row = [&](int row) {
        const float4* hv = reinterpret_cast<const float4*>(&heats[row][0]);
        float4 h0 = hv[0], h1 = hv[1], h2 = hv[2];
        const float hk[NKEY] = {h0.x, h0.y, h0.z, h0.w,
                                h1.x, h1.y, h1.z, h1.w,
                                h2.x, h2.y, h2.z, h2.w};
        float4 o; o.x = o.y = o.z = o.w = 0.0f;
#pragma unroll
        for (int k = 0; k < NKEY; ++k) {
            o.x = fmaf(hk[k], w4[k].x, o.x);
            o.y = fmaf(hk[k], w4[k].y, o.y);
            o.z = fmaf(hk[k], w4[k].z, o.z);
            o.w = fmaf(hk[k], w4[k].w, o.w);
        }
        *reinterpret_cast<float4*>(op + row * NOUT) = o;
    };

#pragma unroll
    for (int s = 0; s < 5; ++s) emit_row(r + 12 * s);  // rows 0..59
    if (r < 4) emit_row(60 + r);                       // rows 60..63
}

// ---------------------------------------------------------------------------
extern "C" void kernel_launch(void* const* d_in, const int* in_sizes, int n_in,
                              void* d_out, int out_size, void* d_ws, size_t ws_size,
                              hipStream_t stream) {
    const int*   seq = (const int*)d_in[0];
    const float* W   = (const float*)d_in[1];
    float*       out = (float*)d_out;

    const int T  = in_sizes[0];     // 524288
    const int nc = T / LC;          // 8192 chunks

    float* Bc = (float*)d_ws;                      // [12][nc]
    float* Cc = Bc + (size_t)NKEY * nc;            // [12][nc]
    float* BG = Cc + (size_t)NKEY * nc;            // [12][256]
    float* CG = BG + (size_t)NKEY * NGRP;          // [12][256]
    float* hs = CG + (size_t)NKEY * NGRP;          // [nc][12]

    hipLaunchKernelGGL(kA, dim3(nc / 128), dim3(128), 0, stream,
                       seq, Bc, Cc, BG, CG, nc);
    hipLaunchKernelGGL(kB, dim3(NKEY), dim3(NGRP), 0, stream,
                       Bc, Cc, BG, CG, hs, nc);
    hipLaunchKernelGGL(kC, dim3(nc), dim3(256), 0, stream,
                       seq, W, hs, out);
}